// Round 1
// baseline (171.488 us; speedup 1.0000x reference)
//
#include <hip/hip_runtime.h>

// Problem constants
#define BATCH   2
#define NPTS    2048
#define MPTS    512
#define BM_TOT  1024     // BATCH*MPTS
#define GVOX    27
#define CRED    32
#define CIG     41       // CRED + 9
#define CAGG    32
#define GCH     864      // GVOX*CAGG
#define CPOST   128

// ---------------------------------------------------------------------------
// Kernel 1: 3-NN search + interpolation + grouped conv (+BN1+ReLU)
// block = one target point m (1024 blocks x 256 threads = 4 waves)
// wave wv handles voxels g = wv, wv+4, ..., wv+24
// ---------------------------------------------------------------------------
__global__ __launch_bounds__(256) void vpa_main(
    const float* __restrict__ sxyz,   // (B*N,3)
    const float* __restrict__ sfeat,  // (B*N,128)
    const float* __restrict__ nxyz,   // (B*M,3)
    const float* __restrict__ wgrp,   // (27,32,41)
    const float* __restrict__ g1, const float* __restrict__ b1,
    const float* __restrict__ m1, const float* __restrict__ v1,
    float* __restrict__ xout)         // (BM,864)
{
    __shared__ float spts[NPTS * 3];  // 24 KB, frame xyz
    __shared__ float lvec[4][CIG];    // per-wave vec row

    const int m    = blockIdx.x;
    const int b    = m >> 9;          // m / MPTS
    const int tid  = threadIdx.x;
    const int lane = tid & 63;
    const int wv   = tid >> 6;

    // stage support xyz for this frame (flat copy, coalesced)
    const float* sx = sxyz + b * (NPTS * 3);
    for (int j = tid; j < NPTS * 3; j += 256) spts[j] = sx[j];

    const float nx = nxyz[m * 3 + 0];
    const float ny = nxyz[m * 3 + 1];
    const float nz = nxyz[m * 3 + 2];
    __syncthreads();

    const float mult = 1.6000000238418579f;   // f32(2.0*2.4/3.0)
    const float INF  = __builtin_inff();

    for (int t = 0; t < 7; ++t) {
        const int  g      = wv + 4 * t;
        const bool active = (g < GVOX);

        float cx = 0.f, cy = 0.f, cz = 0.f;
        float d0 = INF, d1 = INF, d2 = INF;
        int   i0 = 0x7fffffff, i1 = 0x7fffffff, i2 = 0x7fffffff;

        if (active) {
            const int gi = g / 9, rem = g - gi * 9;
            const int gj = rem / 3, gk = rem - gj * 3;
            // exact f32 arithmetic matching the reference grid offsets
            cx = nx + (((float)gi + 0.5f) * mult - 2.4f);
            cy = ny + (((float)gj + 0.5f) * mult - 2.4f);
            cz = nz + (((float)gk + 0.5f) * mult - 2.4f);

            // lane-local 3-NN over 32 interleaved points
            #pragma unroll 8
            for (int k = 0; k < 32; ++k) {
                const int p  = (k << 6) + lane;
                const int p3 = p * 3;
                const float dx = cx - spts[p3 + 0];
                const float dy = cy - spts[p3 + 1];
                const float dz = cz - spts[p3 + 2];
                // exact (no-FMA) d2 in reference order: (x*x + y*y) + z*z
                float dd = __fadd_rn(__fadd_rn(__fmul_rn(dx, dx),
                                               __fmul_rn(dy, dy)),
                                     __fmul_rn(dz, dz));
                const float ch = fmaxf(fmaxf(fabsf(dx), fabsf(dy)), fabsf(dz));
                dd = (ch <= 4.8f) ? dd : INF;
                // branchless sorted insert (strict < keeps lower index first)
                const bool c0 = dd < d0, c1 = dd < d1, c2 = dd < d2;
                d2 = c1 ? d1 : (c2 ? dd : d2);  i2 = c1 ? i1 : (c2 ? p : i2);
                d1 = c0 ? d0 : (c1 ? dd : d1);  i1 = c0 ? i0 : (c1 ? p : i1);
                d0 = c0 ? dd : d0;              i0 = c0 ? p  : i0;
            }

            // wave butterfly merge of sorted-3 lists, lexicographic (d, idx)
            for (int s = 1; s < 64; s <<= 1) {
                const float e0 = __shfl_xor(d0, s);
                const float e1 = __shfl_xor(d1, s);
                const float e2 = __shfl_xor(d2, s);
                const int   j0 = __shfl_xor(i0, s);
                const int   j1 = __shfl_xor(i1, s);
                const int   j2 = __shfl_xor(i2, s);
                {
                    const bool c0 = (e0 < d0) || (e0 == d0 && j0 < i0);
                    const bool c1 = (e0 < d1) || (e0 == d1 && j0 < i1);
                    const bool c2 = (e0 < d2) || (e0 == d2 && j0 < i2);
                    d2 = c1 ? d1 : (c2 ? e0 : d2);  i2 = c1 ? i1 : (c2 ? j0 : i2);
                    d1 = c0 ? d0 : (c1 ? e0 : d1);  i1 = c0 ? i0 : (c1 ? j0 : i1);
                    d0 = c0 ? e0 : d0;              i0 = c0 ? j0 : i0;
                }
                {
                    const bool c0 = (e1 < d0) || (e1 == d0 && j1 < i0);
                    const bool c1 = (e1 < d1) || (e1 == d1 && j1 < i1);
                    const bool c2 = (e1 < d2) || (e1 == d2 && j1 < i2);
                    d2 = c1 ? d1 : (c2 ? e1 : d2);  i2 = c1 ? i1 : (c2 ? j1 : i2);
                    d1 = c0 ? d0 : (c1 ? e1 : d1);  i1 = c0 ? i0 : (c1 ? j1 : i1);
                    d0 = c0 ? e1 : d0;              i0 = c0 ? j1 : i0;
                }
                {
                    const bool c0 = (e2 < d0) || (e2 == d0 && j2 < i0);
                    const bool c1 = (e2 < d1) || (e2 == d1 && j2 < i1);
                    const bool c2 = (e2 < d2) || (e2 == d2 && j2 < i2);
                    d2 = c1 ? d1 : (c2 ? e2 : d2);  i2 = c1 ? i1 : (c2 ? j2 : i2);
                    d1 = c0 ? d0 : (c1 ? e2 : d1);  i1 = c0 ? i0 : (c1 ? j2 : i1);
                    d0 = c0 ? e2 : d0;              i0 = c0 ? j2 : i0;
                }
            }

            // inverse-distance weights (IEEE: 1/inf = 0 handles missing)
            const float r0 = 1.0f / (d0 + 1e-8f);
            const float r1 = 1.0f / (d1 + 1e-8f);
            const float r2 = 1.0f / (d2 + 1e-8f);
            const float rs = fmaxf((r0 + r1) + r2, 1e-8f);
            const float w0 = r0 / rs, w1 = r1 / rs, w2 = r2 / rs;
            const bool  empty = !(d0 < INF);

            const int s0 = (i0 < NPTS) ? i0 : 0;
            const int s1 = (i1 < NPTS) ? i1 : 0;
            const int s2 = (i2 < NPTS) ? i2 : 0;

            float val = 0.0f;
            if (lane < CRED) {
                // fused 128->32 channel fold on the 3 gathered rows
                const float* F  = sfeat + b * (NPTS * 128) + lane;
                const float* p0 = F + s0 * 128;
                const float* p1 = F + s1 * 128;
                const float* p2 = F + s2 * 128;
                const float f0 = ((p0[0] + p0[32]) + p0[64]) + p0[96];
                const float f1 = ((p1[0] + p1[32]) + p1[64]) + p1[96];
                const float f2 = ((p2[0] + p2[32]) + p2[64]) + p2[96];
                val = (w0 * f0 + w1 * f1) + w2 * f2;
            } else if (lane < CIG) {
                const int j  = lane - 32;          // 0..8
                const int k  = j / 3, ax = j - 3 * k;
                const int ik = (k == 0) ? s0 : ((k == 1) ? s1 : s2);
                const float cc = (ax == 0) ? cx : ((ax == 1) ? cy : cz);
                val = cc - spts[ik * 3 + ax];
            }
            if (empty) val = 0.0f;
            if (lane < CIG) lvec[wv][lane] = val;
        }
        __syncthreads();

        // grouped conv (32 outputs per voxel) + BN1 + ReLU
        if (active && lane < CAGG) {
            const int ch = g * CAGG + lane;
            const float* wg = wgrp + ch * CIG;
            float acc = 0.f;
            #pragma unroll
            for (int i = 0; i < CIG; ++i) acc += lvec[wv][i] * wg[i];
            const float sc = g1[ch] * rsqrtf(v1[ch] + 1e-5f);
            const float xv = fmaxf(sc * (acc - m1[ch]) + b1[ch], 0.0f);
            xout[m * GCH + ch] = xv;
        }
        __syncthreads();
    }
}

// ---------------------------------------------------------------------------
// Kernel 2: post MLP  y = x @ w_post^T  (+BN2+ReLU)
// block = 4 target points, 256 threads = 128 out-channels x 2 i-halves
// ---------------------------------------------------------------------------
__global__ __launch_bounds__(256) void vpa_post(
    const float* __restrict__ xin,   // (1024,864)
    const float* __restrict__ wp,    // (128,864)
    const float* __restrict__ g2, const float* __restrict__ b2,
    const float* __restrict__ m2, const float* __restrict__ v2,
    float* __restrict__ out)         // (1024,128)
{
    __shared__ float xs[4 * GCH];       // 13.8 KB
    __shared__ float pb[2][128][4];     // partial sums, 4 KB

    const int mb  = blockIdx.x * 4;
    const int tid = threadIdx.x;

    for (int j = tid; j < 4 * GCH; j += 256) xs[j] = xin[mb * GCH + j];
    __syncthreads();

    const int o = tid & 127;
    const int h = tid >> 7;
    const int ibase = h * (GCH / 2);
    const float* wr = wp + o * GCH + ibase;

    float a0 = 0.f, a1 = 0.f, a2 = 0.f, a3 = 0.f;
    for (int i = 0; i < GCH / 2; ++i) {
        const float w = wr[i];
        const int  ii = ibase + i;
        a0 += xs[0 * GCH + ii] * w;
        a1 += xs[1 * GCH + ii] * w;
        a2 += xs[2 * GCH + ii] * w;
        a3 += xs[3 * GCH + ii] * w;
    }
    pb[h][o][0] = a0; pb[h][o][1] = a1; pb[h][o][2] = a2; pb[h][o][3] = a3;
    __syncthreads();

    if (h == 0) {
        const float sc = g2[o] * rsqrtf(v2[o] + 1e-5f);
        const float mu = m2[o], bt = b2[o];
        #pragma unroll
        for (int mm = 0; mm < 4; ++mm) {
            const float y = pb[0][o][mm] + pb[1][o][mm];
            out[(mb + mm) * CPOST + o] = fmaxf(sc * (y - mu) + bt, 0.0f);
        }
    }
}

// ---------------------------------------------------------------------------
extern "C" void kernel_launch(void* const* d_in, const int* in_sizes, int n_in,
                              void* d_out, int out_size, void* d_ws, size_t ws_size,
                              hipStream_t stream) {
    const float* sxyz  = (const float*)d_in[0];
    const float* sfeat = (const float*)d_in[1];
    const float* nxyz  = (const float*)d_in[2];
    const float* wgrp  = (const float*)d_in[3];
    const float* g1    = (const float*)d_in[4];
    const float* b1    = (const float*)d_in[5];
    const float* m1    = (const float*)d_in[6];
    const float* v1    = (const float*)d_in[7];
    const float* wp    = (const float*)d_in[8];
    const float* g2    = (const float*)d_in[9];
    const float* b2    = (const float*)d_in[10];
    const float* m2    = (const float*)d_in[11];
    const float* v2    = (const float*)d_in[12];

    float* outp = (float*)d_out;
    float* xbuf = (float*)d_ws;   // (1024, 864) f32 = 3.46 MB scratch

    hipLaunchKernelGGL(vpa_main, dim3(BM_TOT), dim3(256), 0, stream,
                       sxyz, sfeat, nxyz, wgrp, g1, b1, m1, v1, xbuf);
    hipLaunchKernelGGL(vpa_post, dim3(BM_TOT / 4), dim3(256), 0, stream,
                       xbuf, wp, g2, b2, m2, v2, outp);
}